// Round 4
// baseline (876.987 us; speedup 1.0000x reference)
//
#include <hip/hip_runtime.h>

// CentroidPool: argmin_k ||x_i - c_k||^2, N=131072, K=1024, D=128, fp32.
// argmin over 0.5*||c_k||^2 - x.c_k (same argmin; x^2 row-constant).
//
// v4: latent rows staged in LDS TRANSPOSED+NEGATED (x_t[d][r], 64 KB,
// stride-1 across lanes -> conflict-free, no compiler register-residency
// gamble). K split across wave pairs (readfirstlane -> provably uniform
// k-base -> coords scalarize to s_load feeding v_fmac_f32). In-block combine.

constexpr int N = 131072;
constexpr int K = 1024;
constexpr int D = 128;
constexpr int CT = 8;     // centroids per inner tile (8 independent FMA chains)
constexpr int ROWS = 128; // latent rows per block
constexpr int KHALF = K / 2;

// Precompute 0.5*||c_k||^2 (4 KB) into ws.
__global__ void centroid_c2_kernel(const float* __restrict__ coords,
                                   float* __restrict__ c2half) {
    int k = blockIdx.x * 256 + threadIdx.x;
    if (k >= K) return;
    const float4* row = reinterpret_cast<const float4*>(coords + k * D);
    float s = 0.f;
#pragma unroll
    for (int i = 0; i < D / 4; ++i) {
        float4 v = row[i];
        s += v.x * v.x + v.y * v.y + v.z * v.z + v.w * v.w;
    }
    c2half[k] = 0.5f * s;
}

__global__ __launch_bounds__(256, 2) void centroid_argmin_kernel(
    const float* __restrict__ latent, const float* __restrict__ coords,
    const float* __restrict__ c2half, int* __restrict__ out) {
    __shared__ float xt[ROWS * D]; // xt[d*ROWS + r] = -latent[row0+r][d], 64 KB
    const int t = threadIdx.x;
    const int row0 = blockIdx.x * ROWS;

    // Stage: 256 threads x (half-row of 64 floats) -> negate + transpose.
    {
        const int r = t & 127;
        const int h = t >> 7; // which d-half this thread stages
        const float4* gp = reinterpret_cast<const float4*>(
            latent + (size_t)(row0 + r) * D + h * 64);
#pragma unroll
        for (int j = 0; j < 16; ++j) {
            float4 v = gp[j];
            int d = h * 64 + j * 4;
            xt[(d + 0) * ROWS + r] = -v.x;
            xt[(d + 1) * ROWS + r] = -v.y;
            xt[(d + 2) * ROWS + r] = -v.z;
            xt[(d + 3) * ROWS + r] = -v.w;
        }
    }
    __syncthreads();

    // Wave w handles rows [(w>>1)*64 .. +64) and K-half (w&1).
    const int w = t >> 6;
    const int lane = t & 63;
    const int r = (w >> 1) * 64 + lane;
    const int khalf = __builtin_amdgcn_readfirstlane(w & 1); // force SGPR
    const int kbase = khalf * KHALF;

    float best = 3.4e38f;
    int bi = kbase;
#pragma unroll 1
    for (int k0 = kbase; k0 < kbase + KHALF; k0 += CT) {
        float acc[CT];
#pragma unroll
        for (int c = 0; c < CT; ++c) acc[c] = c2half[k0 + c]; // s_load
#pragma unroll
        for (int d = 0; d < D; ++d) {
            float xv = xt[d * ROWS + r]; // ds_read_b32, lanes stride-1
#pragma unroll
            for (int c = 0; c < CT; ++c)
                acc[c] = fmaf(xv, coords[(k0 + c) * D + d], acc[c]); // s_load src
        }
        // ascending k + strict '<' == numpy first-occurrence tie-break
#pragma unroll
        for (int c = 0; c < CT; ++c)
            if (acc[c] < best) { best = acc[c]; bi = k0 + c; }
    }

    // Combine the two K-halves per row (reuse LDS; all xt reads are done).
    __syncthreads();
    float* sbest = xt;
    int* sidx = reinterpret_cast<int*>(xt + 256);
    sbest[t] = best;
    sidx[t] = bi;
    __syncthreads();
    if ((w & 1) == 0) { // low-k half owns the write; ties keep lower k
        int o = t ^ 64;
        float ob = sbest[o];
        int oi = sidx[o];
        out[row0 + r] = (ob < best) ? oi : bi;
    }
}

extern "C" void kernel_launch(void* const* d_in, const int* in_sizes, int n_in,
                              void* d_out, int out_size, void* d_ws, size_t ws_size,
                              hipStream_t stream) {
    const float* latent = (const float*)d_in[0];
    const float* coords = (const float*)d_in[1];
    int* out = (int*)d_out;
    float* c2half = (float*)d_ws; // 4 KB

    centroid_c2_kernel<<<(K + 255) / 256, 256, 0, stream>>>(coords, c2half);
    centroid_argmin_kernel<<<N / ROWS, 256, 0, stream>>>(latent, coords, c2half, out);
}

// Round 5
// 459.257 us; speedup vs baseline: 1.9096x; 1.9096x over previous
//
#include <hip/hip_runtime.h>

// CentroidPool: argmin_k ||x_i - c_k||^2, N=131072, K=1024, D=128, fp32.
// = argmin_k (0.5||c_k||^2 - x.c_k). MFMA bf16 hi/lo split (3-term, drop
// lo*lo) + per-row (min, argmin, 2nd-min); rows with gap <= EPS2 are
// recomputed exactly in fp32 (pass B, bit-identical to the r1-proven chain).

constexpr int N = 131072;
constexpr int K = 1024;
constexpr int D = 128;
constexpr float EPS2 = 0.03f; // 2*eps certify margin (worst-case err ~7.5e-3)

typedef __attribute__((ext_vector_type(8))) short short8;
typedef __attribute__((ext_vector_type(16))) float f32x16;

union U8 { uint4 u; short8 s; };
__device__ inline short8 as_s8(uint4 v) { U8 x; x.u = v; return x.s; }

__device__ inline uint bf16rne(float f) {
    uint u = __float_as_uint(f);
    return (u + 0x7fffu + ((u >> 16) & 1u)) >> 16;
}
// pack two floats into bf16x2 hi + bf16x2 lo (lo = exact residual, RNE)
__device__ inline void split2(float a, float b, uint& hi, uint& lo) {
    uint ha = bf16rne(a), hb = bf16rne(b);
    float la = a - __uint_as_float(ha << 16);
    float lb = b - __uint_as_float(hb << 16);
    hi = ha | (hb << 16);
    lo = bf16rne(la) | (bf16rne(lb) << 16);
}

// ---- precompute: 0.5*||c_k||^2 (identical chain to r1, which passed) ----
__global__ void centroid_c2_kernel(const float* __restrict__ coords,
                                   float* __restrict__ c2half) {
    int k = blockIdx.x * 256 + threadIdx.x;
    if (k >= K) return;
    const float4* row = reinterpret_cast<const float4*>(coords + k * D);
    float s = 0.f;
#pragma unroll
    for (int i = 0; i < D / 4; ++i) {
        float4 v = row[i];
        s += v.x * v.x + v.y * v.y + v.z * v.z + v.w * v.w;
    }
    c2half[k] = 0.5f * s;
}

// ---- precompute: coords -> bf16 hi/lo, plain row-major [K][64] dwords ----
__global__ void split_kernel(const float* __restrict__ coords,
                             uint* __restrict__ chi, uint* __restrict__ clo) {
    int g = blockIdx.x * 256 + threadIdx.x; // dword index over K*D/2 = 65536
    float a = coords[2 * g], b = coords[2 * g + 1];
    uint hi, lo;
    split2(a, b, hi, lo);
    chi[g] = hi;
    clo[g] = lo;
}

// staging helpers: 16B group g of tile-row m -> LDS byte m*256 + ((g^(m&15))<<4)
__device__ inline void stage_load(int kt, int tid, const uint* chi,
                                  const uint* clo, uint4& s0, uint4& s1,
                                  uint4& s2, uint4& s3) {
    const int m = tid & 31, gq = tid >> 5;
    const uint* r = chi + (size_t)(kt * 32 + m) * 64;
    s0 = *(const uint4*)(r + gq * 4);
    s1 = *(const uint4*)(r + (gq + 8) * 4);
    const uint* r2 = clo + (size_t)(kt * 32 + m) * 64;
    s2 = *(const uint4*)(r2 + gq * 4);
    s3 = *(const uint4*)(r2 + (gq + 8) * 4);
}
__device__ inline void stage_write(int buf, int tid, const uint4& s0,
                                   const uint4& s1, const uint4& s2,
                                   const uint4& s3, char* smem) {
    const int m = tid & 31, gq = tid >> 5;
    char* hb = smem + buf * 16384;
    *(uint4*)(hb + m * 256 + ((gq ^ (m & 15)) << 4)) = s0;
    *(uint4*)(hb + m * 256 + (((gq + 8) ^ (m & 15)) << 4)) = s1;
    char* lb = hb + 8192;
    *(uint4*)(lb + m * 256 + ((gq ^ (m & 15)) << 4)) = s2;
    *(uint4*)(lb + m * 256 + (((gq + 8) ^ (m & 15)) << 4)) = s3;
}

// latent row -> negated bf16 hi/lo B-fragments (this lane's d-half per chunk)
__device__ inline void load_row(const float* rp, int h, uint4* bh, uint4* bl) {
#pragma unroll
    for (int c = 0; c < 8; ++c) {
        const float* p = rp + 16 * c + 8 * h;
        float4 u = *(const float4*)(p);
        float4 v = *(const float4*)(p + 4);
        uint h0, l0, h1, l1, h2, l2, h3, l3;
        split2(-u.x, -u.y, h0, l0);
        split2(-u.z, -u.w, h1, l1);
        split2(-v.x, -v.y, h2, l2);
        split2(-v.z, -v.w, h3, l3);
        bh[c] = make_uint4(h0, h1, h2, h3);
        bl[c] = make_uint4(l0, l1, l2, l3);
    }
}

// ---- pass A: MFMA approx + (m1,i1,m2) tracking ----
__global__ __launch_bounds__(256, 2) void centroid_mfma_kernel(
    const float* __restrict__ latent, const uint* __restrict__ chi,
    const uint* __restrict__ clo, const float* __restrict__ c2,
    int* __restrict__ out, int* __restrict__ flags) {
    __shared__ __align__(16) char smem[36864]; // 2 bufs x (hi 8K + lo 8K) + c2 4K
    const int tid = threadIdx.x;
    const int l = tid & 63, w = tid >> 6;
    const int m31 = l & 31, h = l >> 5, h4 = h * 4;
    const int rowbase = blockIdx.x * 256 + w * 64;

    // prologue: issue tile-0 coords loads; copy c2; load+split latent; write
    uint4 p0, p1, p2, p3;
    stage_load(0, tid, chi, clo, p0, p1, p2, p3);
    *(float4*)(smem + 32768 + tid * 16) =
        *(const float4*)((const char*)c2 + tid * 16);

    uint4 bh0[8], bl0[8], bh1[8], bl1[8];
    load_row(latent + (size_t)(rowbase + m31) * D, h, bh0, bl0);
    load_row(latent + (size_t)(rowbase + 32 + m31) * D, h, bh1, bl1);
    stage_write(0, tid, p0, p1, p2, p3, smem);
    __syncthreads();

    float m1_0 = 3.4e38f, m2_0 = 3.4e38f, m1_1 = 3.4e38f, m2_1 = 3.4e38f;
    int i1_0 = 0, i1_1 = 0;
    const float* c2l = (const float*)(smem + 32768);

#pragma unroll 1
    for (int t = 0; t < 32; ++t) {
        const int buf = t & 1;
        uint4 s0, s1, s2, s3;
        if (t + 1 < 32) stage_load(t + 1, tid, chi, clo, s0, s1, s2, s3);

        const int k0 = t * 32;
        f32x16 a0, a1;
#pragma unroll
        for (int q = 0; q < 4; ++q) { // acc init = 0.5*c2[k] (LDS broadcast)
            float4 cq = *(const float4*)(c2l + k0 + 8 * q + h4);
            a0[4 * q + 0] = cq.x;
            a0[4 * q + 1] = cq.y;
            a0[4 * q + 2] = cq.z;
            a0[4 * q + 3] = cq.w;
        }
        a1 = a0;

        const char* lhs = smem + buf * 16384;
#pragma unroll
        for (int c = 0; c < 8; ++c) {
            const int sw = (((2 * c + h) ^ (m31 & 15)) << 4) + m31 * 256;
            short8 ahi = *(const short8*)(lhs + sw);
            short8 alo = *(const short8*)(lhs + 8192 + sw);
            a0 = __builtin_amdgcn_mfma_f32_32x32x16_bf16(ahi, as_s8(bh0[c]), a0, 0, 0, 0);
            a1 = __builtin_amdgcn_mfma_f32_32x32x16_bf16(ahi, as_s8(bh1[c]), a1, 0, 0, 0);
            a0 = __builtin_amdgcn_mfma_f32_32x32x16_bf16(ahi, as_s8(bl0[c]), a0, 0, 0, 0);
            a1 = __builtin_amdgcn_mfma_f32_32x32x16_bf16(ahi, as_s8(bl1[c]), a1, 0, 0, 0);
            a0 = __builtin_amdgcn_mfma_f32_32x32x16_bf16(alo, as_s8(bh0[c]), a0, 0, 0, 0);
            a1 = __builtin_amdgcn_mfma_f32_32x32x16_bf16(alo, as_s8(bh1[c]), a1, 0, 0, 0);
        }

        // insert 16 values per tile, ascending k (first-occurrence tie-break)
#pragma unroll
        for (int q = 0; q < 4; ++q) {
#pragma unroll
            for (int j = 0; j < 4; ++j) {
                const int r = 4 * q + j;
                const int kk = k0 + 8 * q + j + h4;
                float v0 = a0[r], v1 = a1[r];
                bool lt0 = v0 < m1_0, lt1 = v1 < m1_1;
                m2_0 = fminf(m2_0, fmaxf(v0, m1_0));
                m2_1 = fminf(m2_1, fmaxf(v1, m1_1));
                m1_0 = fminf(m1_0, v0);
                m1_1 = fminf(m1_1, v1);
                i1_0 = lt0 ? kk : i1_0;
                i1_1 = lt1 ? kk : i1_1;
            }
        }

        if (t + 1 < 32) stage_write(buf ^ 1, tid, s0, s1, s2, s3, smem);
        __syncthreads();
    }

    // merge the two k-halves (lane l <-> l+32); tie -> lower index
    {
        float om = __shfl_xor(m1_0, 32);
        int oi = __shfl_xor(i1_0, 32);
        float o2 = __shfl_xor(m2_0, 32);
        m2_0 = fminf(fminf(m2_0, o2), fmaxf(m1_0, om));
        bool take = (om < m1_0) || (om == m1_0 && oi < i1_0);
        m1_0 = fminf(m1_0, om);
        i1_0 = take ? oi : i1_0;
    }
    {
        float om = __shfl_xor(m1_1, 32);
        int oi = __shfl_xor(i1_1, 32);
        float o2 = __shfl_xor(m2_1, 32);
        m2_1 = fminf(fminf(m2_1, o2), fmaxf(m1_1, om));
        bool take = (om < m1_1) || (om == m1_1 && oi < i1_1);
        m1_1 = fminf(m1_1, om);
        i1_1 = take ? oi : i1_1;
    }
    if (l < 32) {
        int g0 = rowbase + l;
        out[g0] = i1_0;
        flags[g0] = (m2_0 - m1_0) <= EPS2 ? 1 : 0;
        out[g0 + 32] = i1_1;
        flags[g0 + 32] = (m2_1 - m1_1) <= EPS2 ? 1 : 0;
    }
}

// ---- pass B: exact fp32 recompute for flagged rows (r1-proven chain) ----
__global__ __launch_bounds__(256) void centroid_exact_kernel(
    const float* __restrict__ latent, const float* __restrict__ coords,
    const float* __restrict__ c2, const int* __restrict__ flags,
    int* __restrict__ out) {
    const int lane = threadIdx.x & 63;
    const int wid = (blockIdx.x * 256 + threadIdx.x) >> 6;
    const int base = wid * 64;
    unsigned long long mask = __ballot(flags[base + lane] != 0);
    while (mask) {
        const int rbit = __ffsll((unsigned long long)mask) - 1;
        mask &= mask - 1;
        const int row = base + rbit;
        const float* x = latent + (size_t)row * D;
        float m1 = 3.4e38f;
        int i1 = 0;
        for (int kk = 0; kk < 16; kk += 4) { // lane owns k in [lane*16, +16)
            const int k = lane * 16 + kk;
            float acc[4];
#pragma unroll
            for (int c = 0; c < 4; ++c) acc[c] = c2[k + c];
#pragma unroll
            for (int d = 0; d < D; ++d) {
                float xv = -x[d];
#pragma unroll
                for (int c = 0; c < 4; ++c)
                    acc[c] = fmaf(xv, coords[(k + c) * D + d], acc[c]);
            }
#pragma unroll
            for (int c = 0; c < 4; ++c)
                if (acc[c] < m1) { m1 = acc[c]; i1 = k + c; }
        }
#pragma unroll
        for (int off = 32; off; off >>= 1) {
            float om = __shfl_xor(m1, off);
            int oi = __shfl_xor(i1, off);
            if (om < m1 || (om == m1 && oi < i1)) { m1 = om; i1 = oi; }
        }
        if (lane == 0) out[row] = i1;
    }
}

extern "C" void kernel_launch(void* const* d_in, const int* in_sizes, int n_in,
                              void* d_out, int out_size, void* d_ws, size_t ws_size,
                              hipStream_t stream) {
    const float* latent = (const float*)d_in[0];
    const float* coords = (const float*)d_in[1];
    int* out = (int*)d_out;

    char* ws = (char*)d_ws;
    float* c2 = (float*)ws;                       // 4 KB
    uint* chi = (uint*)(ws + 4096);               // 256 KB
    uint* clo = (uint*)(ws + 4096 + 262144);      // 256 KB
    int* flags = (int*)(ws + 4096 + 2 * 262144);  // 512 KB

    centroid_c2_kernel<<<(K + 255) / 256, 256, 0, stream>>>(coords, c2);
    split_kernel<<<(K * D / 2) / 256, 256, 0, stream>>>(coords, chi, clo);
    centroid_mfma_kernel<<<N / 256, 256, 0, stream>>>(latent, chi, clo, c2, out, flags);
    centroid_exact_kernel<<<N / 64 / 4, 256, 0, stream>>>(latent, coords, c2, flags, out);
}

// Round 6
// 285.406 us; speedup vs baseline: 3.0728x; 1.6091x over previous
//
#include <hip/hip_runtime.h>

// CentroidPool: argmin_k ||x_i - c_k||^2, N=131072, K=1024, D=128, fp32.
// = argmin_k (0.5||c_k||^2 - x.c_k). Pass A: MFMA bf16 hi/lo 3-term split +
// per-row (min, argmin, 2nd-min); rows with gap <= EPS2 go to a COMPACT
// worklist (ballot + 1 atomicAdd/wave). Pass B: 4 rows per wave-task,
// fp32 chain bit-identical to the r1-proven kernel, float4 loads.

constexpr int N = 131072;
constexpr int K = 1024;
constexpr int D = 128;
constexpr float EPS2 = 0.05f; // certify margin >> worst-case approx err

typedef __attribute__((ext_vector_type(8))) short short8;
typedef __attribute__((ext_vector_type(16))) float f32x16;

union U8 { uint4 u; short8 s; };
__device__ inline short8 as_s8(uint4 v) { U8 x; x.u = v; return x.s; }

__device__ inline uint bf16rne(float f) {
    uint u = __float_as_uint(f);
    return (u + 0x7fffu + ((u >> 16) & 1u)) >> 16;
}
__device__ inline void split2(float a, float b, uint& hi, uint& lo) {
    uint ha = bf16rne(a), hb = bf16rne(b);
    float la = a - __uint_as_float(ha << 16);
    float lb = b - __uint_as_float(hb << 16);
    hi = ha | (hb << 16);
    lo = bf16rne(la) | (bf16rne(lb) << 16);
}

// ---- precompute: 0.5*||c_k||^2; block 0 also zeroes the worklist counter ----
__global__ void centroid_c2_kernel(const float* __restrict__ coords,
                                   float* __restrict__ c2half,
                                   int* __restrict__ counter) {
    if (blockIdx.x == 0 && threadIdx.x == 0) counter[0] = 0;
    int k = blockIdx.x * 256 + threadIdx.x;
    if (k >= K) return;
    const float4* row = reinterpret_cast<const float4*>(coords + k * D);
    float s = 0.f;
#pragma unroll
    for (int i = 0; i < D / 4; ++i) {
        float4 v = row[i];
        s += v.x * v.x + v.y * v.y + v.z * v.z + v.w * v.w;
    }
    c2half[k] = 0.5f * s;
}

// ---- precompute: coords -> bf16 hi/lo, row-major [K][64] dwords ----
__global__ void split_kernel(const float* __restrict__ coords,
                             uint* __restrict__ chi, uint* __restrict__ clo) {
    int g = blockIdx.x * 256 + threadIdx.x;
    float a = coords[2 * g], b = coords[2 * g + 1];
    uint hi, lo;
    split2(a, b, hi, lo);
    chi[g] = hi;
    clo[g] = lo;
}

__device__ inline void stage_load(int kt, int tid, const uint* chi,
                                  const uint* clo, uint4& s0, uint4& s1,
                                  uint4& s2, uint4& s3) {
    const int m = tid & 31, gq = tid >> 5;
    const uint* r = chi + (size_t)(kt * 32 + m) * 64;
    s0 = *(const uint4*)(r + gq * 4);
    s1 = *(const uint4*)(r + (gq + 8) * 4);
    const uint* r2 = clo + (size_t)(kt * 32 + m) * 64;
    s2 = *(const uint4*)(r2 + gq * 4);
    s3 = *(const uint4*)(r2 + (gq + 8) * 4);
}
__device__ inline void stage_write(int buf, int tid, const uint4& s0,
                                   const uint4& s1, const uint4& s2,
                                   const uint4& s3, char* smem) {
    const int m = tid & 31, gq = tid >> 5;
    char* hb = smem + buf * 16384;
    *(uint4*)(hb + m * 256 + ((gq ^ (m & 15)) << 4)) = s0;
    *(uint4*)(hb + m * 256 + (((gq + 8) ^ (m & 15)) << 4)) = s1;
    char* lb = hb + 8192;
    *(uint4*)(lb + m * 256 + ((gq ^ (m & 15)) << 4)) = s2;
    *(uint4*)(lb + m * 256 + (((gq + 8) ^ (m & 15)) << 4)) = s3;
}

__device__ inline void load_row(const float* rp, int h, uint4* bh, uint4* bl) {
#pragma unroll
    for (int c = 0; c < 8; ++c) {
        const float* p = rp + 16 * c + 8 * h;
        float4 u = *(const float4*)(p);
        float4 v = *(const float4*)(p + 4);
        uint h0, l0, h1, l1, h2, l2, h3, l3;
        split2(-u.x, -u.y, h0, l0);
        split2(-u.z, -u.w, h1, l1);
        split2(-v.x, -v.y, h2, l2);
        split2(-v.z, -v.w, h3, l3);
        bh[c] = make_uint4(h0, h1, h2, h3);
        bl[c] = make_uint4(l0, l1, l2, l3);
    }
}

// ---- pass A: MFMA approx + (m1,i1,m2) tracking + compact flagged list ----
__global__ __launch_bounds__(256, 2) void centroid_mfma_kernel(
    const float* __restrict__ latent, const uint* __restrict__ chi,
    const uint* __restrict__ clo, const float* __restrict__ c2,
    int* __restrict__ out, int* __restrict__ counter, int* __restrict__ list) {
    __shared__ __align__(16) char smem[36864];
    const int tid = threadIdx.x;
    const int l = tid & 63, w = tid >> 6;
    const int m31 = l & 31, h = l >> 5, h4 = h * 4;
    const int rowbase = blockIdx.x * 256 + w * 64;

    uint4 p0, p1, p2, p3;
    stage_load(0, tid, chi, clo, p0, p1, p2, p3);
    *(float4*)(smem + 32768 + tid * 16) =
        *(const float4*)((const char*)c2 + tid * 16);

    uint4 bh0[8], bl0[8], bh1[8], bl1[8];
    load_row(latent + (size_t)(rowbase + m31) * D, h, bh0, bl0);
    load_row(latent + (size_t)(rowbase + 32 + m31) * D, h, bh1, bl1);
    stage_write(0, tid, p0, p1, p2, p3, smem);
    __syncthreads();

    float m1_0 = 3.4e38f, m2_0 = 3.4e38f, m1_1 = 3.4e38f, m2_1 = 3.4e38f;
    int i1_0 = 0, i1_1 = 0;
    const float* c2l = (const float*)(smem + 32768);

#pragma unroll 1
    for (int t = 0; t < 32; ++t) {
        const int buf = t & 1;
        uint4 s0, s1, s2, s3;
        if (t + 1 < 32) stage_load(t + 1, tid, chi, clo, s0, s1, s2, s3);

        const int k0 = t * 32;
        f32x16 a0, a1;
#pragma unroll
        for (int q = 0; q < 4; ++q) {
            float4 cq = *(const float4*)(c2l + k0 + 8 * q + h4);
            a0[4 * q + 0] = cq.x;
            a0[4 * q + 1] = cq.y;
            a0[4 * q + 2] = cq.z;
            a0[4 * q + 3] = cq.w;
        }
        a1 = a0;

        const char* lhs = smem + buf * 16384;
#pragma unroll
        for (int c = 0; c < 8; ++c) {
            const int sw = (((2 * c + h) ^ (m31 & 15)) << 4) + m31 * 256;
            short8 ahi = *(const short8*)(lhs + sw);
            short8 alo = *(const short8*)(lhs + 8192 + sw);
            a0 = __builtin_amdgcn_mfma_f32_32x32x16_bf16(ahi, as_s8(bh0[c]), a0, 0, 0, 0);
            a1 = __builtin_amdgcn_mfma_f32_32x32x16_bf16(ahi, as_s8(bh1[c]), a1, 0, 0, 0);
            a0 = __builtin_amdgcn_mfma_f32_32x32x16_bf16(ahi, as_s8(bl0[c]), a0, 0, 0, 0);
            a1 = __builtin_amdgcn_mfma_f32_32x32x16_bf16(ahi, as_s8(bl1[c]), a1, 0, 0, 0);
            a0 = __builtin_amdgcn_mfma_f32_32x32x16_bf16(alo, as_s8(bh0[c]), a0, 0, 0, 0);
            a1 = __builtin_amdgcn_mfma_f32_32x32x16_bf16(alo, as_s8(bh1[c]), a1, 0, 0, 0);
        }

#pragma unroll
        for (int q = 0; q < 4; ++q) {
#pragma unroll
            for (int j = 0; j < 4; ++j) {
                const int r = 4 * q + j;
                const int kk = k0 + 8 * q + j + h4;
                float v0 = a0[r], v1 = a1[r];
                bool lt0 = v0 < m1_0, lt1 = v1 < m1_1;
                m2_0 = fminf(m2_0, fmaxf(v0, m1_0));
                m2_1 = fminf(m2_1, fmaxf(v1, m1_1));
                m1_0 = fminf(m1_0, v0);
                m1_1 = fminf(m1_1, v1);
                i1_0 = lt0 ? kk : i1_0;
                i1_1 = lt1 ? kk : i1_1;
            }
        }

        if (t + 1 < 32) stage_write(buf ^ 1, tid, s0, s1, s2, s3, smem);
        __syncthreads();
    }

    // merge the two k-halves (lane l <-> l+32); tie -> lower k
    {
        float om = __shfl_xor(m1_0, 32);
        int oi = __shfl_xor(i1_0, 32);
        float o2 = __shfl_xor(m2_0, 32);
        m2_0 = fminf(fminf(m2_0, o2), fmaxf(m1_0, om));
        bool take = (om < m1_0) || (om == m1_0 && oi < i1_0);
        m1_0 = fminf(m1_0, om);
        i1_0 = take ? oi : i1_0;
    }
    {
        float om = __shfl_xor(m1_1, 32);
        int oi = __shfl_xor(i1_1, 32);
        float o2 = __shfl_xor(m2_1, 32);
        m2_1 = fminf(fminf(m2_1, o2), fmaxf(m1_1, om));
        bool take = (om < m1_1) || (om == m1_1 && oi < i1_1);
        m1_1 = fminf(m1_1, om);
        i1_1 = take ? oi : i1_1;
    }

    // lane l owns row rowbase+l (merged state valid on all lanes)
    const float mym1 = (l < 32) ? m1_0 : m1_1;
    const float mym2 = (l < 32) ? m2_0 : m2_1;
    const int myi = (l < 32) ? i1_0 : i1_1;
    out[rowbase + l] = myi;

    const bool flg = (mym2 - mym1) <= EPS2;
    unsigned long long bm = __ballot(flg);
    int cnt = __popcll(bm);
    int pos = 0;
    if (l == 0 && cnt) pos = atomicAdd(counter, cnt);
    pos = __shfl(pos, 0);
    if (flg)
        list[pos + __popcll(bm & ((1ull << l) - 1ull))] = rowbase + l;
}

// ---- pass B: exact fp32 recompute, 4 rows per wave-task, grid-stride ----
__global__ __launch_bounds__(256) void centroid_exact_kernel(
    const float* __restrict__ latent, const float* __restrict__ coords,
    const float* __restrict__ c2, const int* __restrict__ cnt_list,
    int* __restrict__ out) {
    const int count = cnt_list[0];
    const int* list = cnt_list + 16;
    const int lane = threadIdx.x & 63;
    const int gw = (blockIdx.x * 256 + threadIdx.x) >> 6;
    const int nwaves = gridDim.x * 4;
    const int k0 = lane * 16; // lane owns k in [k0, k0+16), ascending with lane

    for (int task = gw; task * 4 < count; task += nwaves) {
        const int base = task * 4;
        const int nr = min(4, count - base);
        const float* xp[4];
        int rows[4];
#pragma unroll
        for (int j = 0; j < 4; ++j) {
            int idx = base + (j < nr ? j : nr - 1);
            rows[j] = __builtin_amdgcn_readfirstlane(list[idx]);
            xp[j] = latent + (size_t)rows[j] * D;
        }

        float acc[16][4];
#pragma unroll
        for (int c = 0; c < 16; ++c) {
            float cc = c2[k0 + c];
#pragma unroll
            for (int j = 0; j < 4; ++j) acc[c][j] = cc;
        }

#pragma unroll 1
        for (int d4 = 0; d4 < D / 4; ++d4) { // fmaf order == r1-proven chain
            float4 xq[4];
#pragma unroll
            for (int j = 0; j < 4; ++j)
                xq[j] = *(const float4*)(xp[j] + 4 * d4);
#pragma unroll
            for (int c = 0; c < 16; ++c) {
                float4 cq = *(const float4*)(coords + (size_t)(k0 + c) * D + 4 * d4);
#pragma unroll
                for (int j = 0; j < 4; ++j) {
                    acc[c][j] = fmaf(-xq[j].x, cq.x, acc[c][j]);
                    acc[c][j] = fmaf(-xq[j].y, cq.y, acc[c][j]);
                    acc[c][j] = fmaf(-xq[j].z, cq.z, acc[c][j]);
                    acc[c][j] = fmaf(-xq[j].w, cq.w, acc[c][j]);
                }
            }
        }

#pragma unroll
        for (int j = 0; j < 4; ++j) {
            float m1 = acc[0][j];
            int i1 = k0;
#pragma unroll
            for (int c = 1; c < 16; ++c)
                if (acc[c][j] < m1) { m1 = acc[c][j]; i1 = k0 + c; }
#pragma unroll
            for (int off = 1; off < 64; off <<= 1) {
                float om = __shfl_xor(m1, off);
                int oi = __shfl_xor(i1, off);
                if (om < m1 || (om == m1 && oi < i1)) { m1 = om; i1 = oi; }
            }
            if (lane == 0 && j < nr) out[rows[j]] = i1;
        }
    }
}

extern "C" void kernel_launch(void* const* d_in, const int* in_sizes, int n_in,
                              void* d_out, int out_size, void* d_ws, size_t ws_size,
                              hipStream_t stream) {
    const float* latent = (const float*)d_in[0];
    const float* coords = (const float*)d_in[1];
    int* out = (int*)d_out;

    char* ws = (char*)d_ws;
    float* c2 = (float*)ws;                        // 4 KB
    uint* chi = (uint*)(ws + 4096);                // 256 KB
    uint* clo = (uint*)(ws + 4096 + 262144);       // 256 KB
    int* cnt_list = (int*)(ws + 4096 + 2 * 262144); // 64 B counter + 512 KB list
    int* counter = cnt_list;
    int* list = cnt_list + 16;

    centroid_c2_kernel<<<(K + 255) / 256, 256, 0, stream>>>(coords, c2, counter);
    split_kernel<<<(K * D / 2) / 256, 256, 0, stream>>>(coords, chi, clo);
    centroid_mfma_kernel<<<N / 256, 256, 0, stream>>>(latent, chi, clo, c2, out,
                                                      counter, list);
    centroid_exact_kernel<<<256, 256, 0, stream>>>(latent, coords, c2, cnt_list, out);
}

// Round 7
// 273.615 us; speedup vs baseline: 3.2052x; 1.0431x over previous
//
#include <hip/hip_runtime.h>

// CentroidPool: argmin_k ||x_i - c_k||^2, N=131072, K=1024, D=128, fp32.
// = argmin_k (0.5||c_k||^2 - x.c_k). Pass A: MFMA bf16 hi/lo 3-term split +
// per-row (min, argmin, 2nd-min); rows with gap <= EPS2 go to a COMPACT
// worklist (ballot + 1 atomicAdd/wave). Pass B: 4 rows per wave-task,
// fp32 chain bit-identical to the r1-proven kernel, float4 loads.
// r7: pass B grid 256 -> 2048 blocks (was 1 block/CU -> latency-serialized
// L2 loads at 9% occupancy, 6.6% VALUBusy; 78us/task vs 7us FMA-bound).

constexpr int N = 131072;
constexpr int K = 1024;
constexpr int D = 128;
constexpr float EPS2 = 0.05f; // certify margin >> worst-case approx err (~6e-3)

typedef __attribute__((ext_vector_type(8))) short short8;
typedef __attribute__((ext_vector_type(16))) float f32x16;

union U8 { uint4 u; short8 s; };
__device__ inline short8 as_s8(uint4 v) { U8 x; x.u = v; return x.s; }

__device__ inline uint bf16rne(float f) {
    uint u = __float_as_uint(f);
    return (u + 0x7fffu + ((u >> 16) & 1u)) >> 16;
}
__device__ inline void split2(float a, float b, uint& hi, uint& lo) {
    uint ha = bf16rne(a), hb = bf16rne(b);
    float la = a - __uint_as_float(ha << 16);
    float lb = b - __uint_as_float(hb << 16);
    hi = ha | (hb << 16);
    lo = bf16rne(la) | (bf16rne(lb) << 16);
}

// ---- precompute: 0.5*||c_k||^2; block 0 also zeroes the worklist counter ----
__global__ void centroid_c2_kernel(const float* __restrict__ coords,
                                   float* __restrict__ c2half,
                                   int* __restrict__ counter) {
    if (blockIdx.x == 0 && threadIdx.x == 0) counter[0] = 0;
    int k = blockIdx.x * 256 + threadIdx.x;
    if (k >= K) return;
    const float4* row = reinterpret_cast<const float4*>(coords + k * D);
    float s = 0.f;
#pragma unroll
    for (int i = 0; i < D / 4; ++i) {
        float4 v = row[i];
        s += v.x * v.x + v.y * v.y + v.z * v.z + v.w * v.w;
    }
    c2half[k] = 0.5f * s;
}

// ---- precompute: coords -> bf16 hi/lo, row-major [K][64] dwords ----
__global__ void split_kernel(const float* __restrict__ coords,
                             uint* __restrict__ chi, uint* __restrict__ clo) {
    int g = blockIdx.x * 256 + threadIdx.x;
    float a = coords[2 * g], b = coords[2 * g + 1];
    uint hi, lo;
    split2(a, b, hi, lo);
    chi[g] = hi;
    clo[g] = lo;
}

__device__ inline void stage_load(int kt, int tid, const uint* chi,
                                  const uint* clo, uint4& s0, uint4& s1,
                                  uint4& s2, uint4& s3) {
    const int m = tid & 31, gq = tid >> 5;
    const uint* r = chi + (size_t)(kt * 32 + m) * 64;
    s0 = *(const uint4*)(r + gq * 4);
    s1 = *(const uint4*)(r + (gq + 8) * 4);
    const uint* r2 = clo + (size_t)(kt * 32 + m) * 64;
    s2 = *(const uint4*)(r2 + gq * 4);
    s3 = *(const uint4*)(r2 + (gq + 8) * 4);
}
__device__ inline void stage_write(int buf, int tid, const uint4& s0,
                                   const uint4& s1, const uint4& s2,
                                   const uint4& s3, char* smem) {
    const int m = tid & 31, gq = tid >> 5;
    char* hb = smem + buf * 16384;
    *(uint4*)(hb + m * 256 + ((gq ^ (m & 15)) << 4)) = s0;
    *(uint4*)(hb + m * 256 + (((gq + 8) ^ (m & 15)) << 4)) = s1;
    char* lb = hb + 8192;
    *(uint4*)(lb + m * 256 + ((gq ^ (m & 15)) << 4)) = s2;
    *(uint4*)(lb + m * 256 + (((gq + 8) ^ (m & 15)) << 4)) = s3;
}

__device__ inline void load_row(const float* rp, int h, uint4* bh, uint4* bl) {
#pragma unroll
    for (int c = 0; c < 8; ++c) {
        const float* p = rp + 16 * c + 8 * h;
        float4 u = *(const float4*)(p);
        float4 v = *(const float4*)(p + 4);
        uint h0, l0, h1, l1, h2, l2, h3, l3;
        split2(-u.x, -u.y, h0, l0);
        split2(-u.z, -u.w, h1, l1);
        split2(-v.x, -v.y, h2, l2);
        split2(-v.z, -v.w, h3, l3);
        bh[c] = make_uint4(h0, h1, h2, h3);
        bl[c] = make_uint4(l0, l1, l2, l3);
    }
}

// ---- pass A: MFMA approx + (m1,i1,m2) tracking + compact flagged list ----
__global__ __launch_bounds__(256, 2) void centroid_mfma_kernel(
    const float* __restrict__ latent, const uint* __restrict__ chi,
    const uint* __restrict__ clo, const float* __restrict__ c2,
    int* __restrict__ out, int* __restrict__ counter, int* __restrict__ list) {
    __shared__ __align__(16) char smem[36864];
    const int tid = threadIdx.x;
    const int l = tid & 63, w = tid >> 6;
    const int m31 = l & 31, h = l >> 5, h4 = h * 4;
    const int rowbase = blockIdx.x * 256 + w * 64;

    uint4 p0, p1, p2, p3;
    stage_load(0, tid, chi, clo, p0, p1, p2, p3);
    *(float4*)(smem + 32768 + tid * 16) =
        *(const float4*)((const char*)c2 + tid * 16);

    uint4 bh0[8], bl0[8], bh1[8], bl1[8];
    load_row(latent + (size_t)(rowbase + m31) * D, h, bh0, bl0);
    load_row(latent + (size_t)(rowbase + 32 + m31) * D, h, bh1, bl1);
    stage_write(0, tid, p0, p1, p2, p3, smem);
    __syncthreads();

    float m1_0 = 3.4e38f, m2_0 = 3.4e38f, m1_1 = 3.4e38f, m2_1 = 3.4e38f;
    int i1_0 = 0, i1_1 = 0;
    const float* c2l = (const float*)(smem + 32768);

#pragma unroll 1
    for (int t = 0; t < 32; ++t) {
        const int buf = t & 1;
        uint4 s0, s1, s2, s3;
        if (t + 1 < 32) stage_load(t + 1, tid, chi, clo, s0, s1, s2, s3);

        const int k0 = t * 32;
        f32x16 a0, a1;
#pragma unroll
        for (int q = 0; q < 4; ++q) {
            float4 cq = *(const float4*)(c2l + k0 + 8 * q + h4);
            a0[4 * q + 0] = cq.x;
            a0[4 * q + 1] = cq.y;
            a0[4 * q + 2] = cq.z;
            a0[4 * q + 3] = cq.w;
        }
        a1 = a0;

        const char* lhs = smem + buf * 16384;
#pragma unroll
        for (int c = 0; c < 8; ++c) {
            const int sw = (((2 * c + h) ^ (m31 & 15)) << 4) + m31 * 256;
            short8 ahi = *(const short8*)(lhs + sw);
            short8 alo = *(const short8*)(lhs + 8192 + sw);
            a0 = __builtin_amdgcn_mfma_f32_32x32x16_bf16(ahi, as_s8(bh0[c]), a0, 0, 0, 0);
            a1 = __builtin_amdgcn_mfma_f32_32x32x16_bf16(ahi, as_s8(bh1[c]), a1, 0, 0, 0);
            a0 = __builtin_amdgcn_mfma_f32_32x32x16_bf16(ahi, as_s8(bl0[c]), a0, 0, 0, 0);
            a1 = __builtin_amdgcn_mfma_f32_32x32x16_bf16(ahi, as_s8(bl1[c]), a1, 0, 0, 0);
            a0 = __builtin_amdgcn_mfma_f32_32x32x16_bf16(alo, as_s8(bh0[c]), a0, 0, 0, 0);
            a1 = __builtin_amdgcn_mfma_f32_32x32x16_bf16(alo, as_s8(bh1[c]), a1, 0, 0, 0);
        }

#pragma unroll
        for (int q = 0; q < 4; ++q) {
#pragma unroll
            for (int j = 0; j < 4; ++j) {
                const int r = 4 * q + j;
                const int kk = k0 + 8 * q + j + h4;
                float v0 = a0[r], v1 = a1[r];
                bool lt0 = v0 < m1_0, lt1 = v1 < m1_1;
                m2_0 = fminf(m2_0, fmaxf(v0, m1_0));
                m2_1 = fminf(m2_1, fmaxf(v1, m1_1));
                m1_0 = fminf(m1_0, v0);
                m1_1 = fminf(m1_1, v1);
                i1_0 = lt0 ? kk : i1_0;
                i1_1 = lt1 ? kk : i1_1;
            }
        }

        if (t + 1 < 32) stage_write(buf ^ 1, tid, s0, s1, s2, s3, smem);
        __syncthreads();
    }

    // merge the two k-halves (lane l <-> l+32); tie -> lower k
    {
        float om = __shfl_xor(m1_0, 32);
        int oi = __shfl_xor(i1_0, 32);
        float o2 = __shfl_xor(m2_0, 32);
        m2_0 = fminf(fminf(m2_0, o2), fmaxf(m1_0, om));
        bool take = (om < m1_0) || (om == m1_0 && oi < i1_0);
        m1_0 = fminf(m1_0, om);
        i1_0 = take ? oi : i1_0;
    }
    {
        float om = __shfl_xor(m1_1, 32);
        int oi = __shfl_xor(i1_1, 32);
        float o2 = __shfl_xor(m2_1, 32);
        m2_1 = fminf(fminf(m2_1, o2), fmaxf(m1_1, om));
        bool take = (om < m1_1) || (om == m1_1 && oi < i1_1);
        m1_1 = fminf(m1_1, om);
        i1_1 = take ? oi : i1_1;
    }

    // lane l owns row rowbase+l (merged state valid on all lanes)
    const float mym1 = (l < 32) ? m1_0 : m1_1;
    const float mym2 = (l < 32) ? m2_0 : m2_1;
    const int myi = (l < 32) ? i1_0 : i1_1;
    out[rowbase + l] = myi;

    const bool flg = (mym2 - mym1) <= EPS2;
    unsigned long long bm = __ballot(flg);
    int cnt = __popcll(bm);
    int pos = 0;
    if (l == 0 && cnt) pos = atomicAdd(counter, cnt);
    pos = __shfl(pos, 0);
    if (flg)
        list[pos + __popcll(bm & ((1ull << l) - 1ull))] = rowbase + l;
}

// ---- pass B: exact fp32 recompute, 4 rows per wave-task, grid-stride ----
__global__ __launch_bounds__(256) void centroid_exact_kernel(
    const float* __restrict__ latent, const float* __restrict__ coords,
    const float* __restrict__ c2, const int* __restrict__ cnt_list,
    int* __restrict__ out) {
    const int count = cnt_list[0];
    const int* list = cnt_list + 16;
    const int lane = threadIdx.x & 63;
    const int gw = (blockIdx.x * 256 + threadIdx.x) >> 6;
    const int nwaves = gridDim.x * 4;
    const int k0 = lane * 16; // lane owns k in [k0, k0+16), ascending with lane

    for (int task = gw; task * 4 < count; task += nwaves) {
        const int base = task * 4;
        const int nr = min(4, count - base);
        const float* xp[4];
        int rows[4];
#pragma unroll
        for (int j = 0; j < 4; ++j) {
            int idx = base + (j < nr ? j : nr - 1);
            rows[j] = __builtin_amdgcn_readfirstlane(list[idx]);
            xp[j] = latent + (size_t)rows[j] * D;
        }

        float acc[16][4];
#pragma unroll
        for (int c = 0; c < 16; ++c) {
            float cc = c2[k0 + c];
#pragma unroll
            for (int j = 0; j < 4; ++j) acc[c][j] = cc;
        }

#pragma unroll 1
        for (int d4 = 0; d4 < D / 4; ++d4) { // fmaf order == r1-proven chain
            float4 xq[4];
#pragma unroll
            for (int j = 0; j < 4; ++j)
                xq[j] = *(const float4*)(xp[j] + 4 * d4);
#pragma unroll
            for (int c = 0; c < 16; ++c) {
                float4 cq = *(const float4*)(coords + (size_t)(k0 + c) * D + 4 * d4);
#pragma unroll
                for (int j = 0; j < 4; ++j) {
                    acc[c][j] = fmaf(-xq[j].x, cq.x, acc[c][j]);
                    acc[c][j] = fmaf(-xq[j].y, cq.y, acc[c][j]);
                    acc[c][j] = fmaf(-xq[j].z, cq.z, acc[c][j]);
                    acc[c][j] = fmaf(-xq[j].w, cq.w, acc[c][j]);
                }
            }
        }

#pragma unroll
        for (int j = 0; j < 4; ++j) {
            float m1 = acc[0][j];
            int i1 = k0;
#pragma unroll
            for (int c = 1; c < 16; ++c)
                if (acc[c][j] < m1) { m1 = acc[c][j]; i1 = k0 + c; }
#pragma unroll
            for (int off = 1; off < 64; off <<= 1) {
                float om = __shfl_xor(m1, off);
                int oi = __shfl_xor(i1, off);
                if (om < m1 || (om == m1 && oi < i1)) { m1 = om; i1 = oi; }
            }
            if (lane == 0 && j < nr) out[rows[j]] = i1;
        }
    }
}

extern "C" void kernel_launch(void* const* d_in, const int* in_sizes, int n_in,
                              void* d_out, int out_size, void* d_ws, size_t ws_size,
                              hipStream_t stream) {
    const float* latent = (const float*)d_in[0];
    const float* coords = (const float*)d_in[1];
    int* out = (int*)d_out;

    char* ws = (char*)d_ws;
    float* c2 = (float*)ws;                        // 4 KB
    uint* chi = (uint*)(ws + 4096);                // 256 KB
    uint* clo = (uint*)(ws + 4096 + 262144);       // 256 KB
    int* cnt_list = (int*)(ws + 4096 + 2 * 262144); // 64 B counter + 512 KB list
    int* counter = cnt_list;
    int* list = cnt_list + 16;

    centroid_c2_kernel<<<(K + 255) / 256, 256, 0, stream>>>(coords, c2, counter);
    split_kernel<<<(K * D / 2) / 256, 256, 0, stream>>>(coords, chi, clo);
    centroid_mfma_kernel<<<N / 256, 256, 0, stream>>>(latent, chi, clo, c2, out,
                                                      counter, list);
    // 2048 blocks = 8 blocks/CU: latency hiding for the L2-resident coords
    // streaming (256 blocks was 1 block/CU -> 9% occupancy, serialized loads)
    centroid_exact_kernel<<<2048, 256, 0, stream>>>(latent, coords, c2, cnt_list, out);
}

// Round 8
// 156.156 us; speedup vs baseline: 5.6161x; 1.7522x over previous
//
#include <hip/hip_runtime.h>

// CentroidPool: argmin_k ||x_i - c_k||^2, N=131072, K=1024, D=128, fp32.
// = argmin_k (0.5||c_k||^2 - x.c_k). Pass A: MFMA bf16 hi/lo 3-term split +
// per-row (min, argmin, 2nd-min); rows with gap <= EPS2 go to a COMPACT
// worklist. Pass B: exact fp32 recompute from coordsT [D][K] with k=c*64+lane
// ownership -> coalesced coords reads (r7's lane*16 layout hit 64 cache
// lines/load = 150us single-task latency; more waves couldn't help).

constexpr int N = 131072;
constexpr int K = 1024;
constexpr int D = 128;
constexpr float EPS2 = 0.05f; // certify margin >> worst-case approx err (~1e-3)

typedef __attribute__((ext_vector_type(8))) short short8;
typedef __attribute__((ext_vector_type(16))) float f32x16;

union U8 { uint4 u; short8 s; };
__device__ inline short8 as_s8(uint4 v) { U8 x; x.u = v; return x.s; }

__device__ inline uint bf16rne(float f) {
    uint u = __float_as_uint(f);
    return (u + 0x7fffu + ((u >> 16) & 1u)) >> 16;
}
__device__ inline void split2(float a, float b, uint& hi, uint& lo) {
    uint ha = bf16rne(a), hb = bf16rne(b);
    float la = a - __uint_as_float(ha << 16);
    float lb = b - __uint_as_float(hb << 16);
    hi = ha | (hb << 16);
    lo = bf16rne(la) | (bf16rne(lb) << 16);
}

// ---- precompute: 0.5*||c_k||^2; block 0 also zeroes the worklist counter ----
__global__ void centroid_c2_kernel(const float* __restrict__ coords,
                                   float* __restrict__ c2half,
                                   int* __restrict__ counter) {
    if (blockIdx.x == 0 && threadIdx.x == 0) counter[0] = 0;
    int k = blockIdx.x * 256 + threadIdx.x;
    if (k >= K) return;
    const float4* row = reinterpret_cast<const float4*>(coords + k * D);
    float s = 0.f;
#pragma unroll
    for (int i = 0; i < D / 4; ++i) {
        float4 v = row[i];
        s += v.x * v.x + v.y * v.y + v.z * v.z + v.w * v.w;
    }
    c2half[k] = 0.5f * s;
}

// ---- precompute: coords -> bf16 hi/lo, row-major [K][64] dwords ----
__global__ void split_kernel(const float* __restrict__ coords,
                             uint* __restrict__ chi, uint* __restrict__ clo) {
    int g = blockIdx.x * 256 + threadIdx.x;
    float a = coords[2 * g], b = coords[2 * g + 1];
    uint hi, lo;
    split2(a, b, hi, lo);
    chi[g] = hi;
    clo[g] = lo;
}

// ---- precompute: coordsT[d][k] = coords[k][d] (LDS-tiled, coalesced) ----
__global__ __launch_bounds__(256) void transpose_kernel(
    const float* __restrict__ coords, float* __restrict__ coordsT) {
    __shared__ float tile[64][65];
    const int k0 = blockIdx.x * 64; // 16 k-tiles
    const int d0 = blockIdx.y * 64; // 2 d-tiles
    const int tx = threadIdx.x & 63, ty = threadIdx.x >> 6;
#pragma unroll
    for (int i = 0; i < 64; i += 4)
        tile[ty + i][tx] = coords[(size_t)(k0 + ty + i) * D + d0 + tx];
    __syncthreads();
#pragma unroll
    for (int i = 0; i < 64; i += 4)
        coordsT[(size_t)(d0 + ty + i) * K + k0 + tx] = tile[tx][ty + i];
}

__device__ inline void stage_load(int kt, int tid, const uint* chi,
                                  const uint* clo, uint4& s0, uint4& s1,
                                  uint4& s2, uint4& s3) {
    const int m = tid & 31, gq = tid >> 5;
    const uint* r = chi + (size_t)(kt * 32 + m) * 64;
    s0 = *(const uint4*)(r + gq * 4);
    s1 = *(const uint4*)(r + (gq + 8) * 4);
    const uint* r2 = clo + (size_t)(kt * 32 + m) * 64;
    s2 = *(const uint4*)(r2 + gq * 4);
    s3 = *(const uint4*)(r2 + (gq + 8) * 4);
}
__device__ inline void stage_write(int buf, int tid, const uint4& s0,
                                   const uint4& s1, const uint4& s2,
                                   const uint4& s3, char* smem) {
    const int m = tid & 31, gq = tid >> 5;
    char* hb = smem + buf * 16384;
    *(uint4*)(hb + m * 256 + ((gq ^ (m & 15)) << 4)) = s0;
    *(uint4*)(hb + m * 256 + (((gq + 8) ^ (m & 15)) << 4)) = s1;
    char* lb = hb + 8192;
    *(uint4*)(lb + m * 256 + ((gq ^ (m & 15)) << 4)) = s2;
    *(uint4*)(lb + m * 256 + (((gq + 8) ^ (m & 15)) << 4)) = s3;
}

__device__ inline void load_row(const float* rp, int h, uint4* bh, uint4* bl) {
#pragma unroll
    for (int c = 0; c < 8; ++c) {
        const float* p = rp + 16 * c + 8 * h;
        float4 u = *(const float4*)(p);
        float4 v = *(const float4*)(p + 4);
        uint h0, l0, h1, l1, h2, l2, h3, l3;
        split2(-u.x, -u.y, h0, l0);
        split2(-u.z, -u.w, h1, l1);
        split2(-v.x, -v.y, h2, l2);
        split2(-v.z, -v.w, h3, l3);
        bh[c] = make_uint4(h0, h1, h2, h3);
        bl[c] = make_uint4(l0, l1, l2, l3);
    }
}

// ---- pass A: MFMA approx + (m1,i1,m2) tracking + compact flagged list ----
__global__ __launch_bounds__(256, 2) void centroid_mfma_kernel(
    const float* __restrict__ latent, const uint* __restrict__ chi,
    const uint* __restrict__ clo, const float* __restrict__ c2,
    int* __restrict__ out, int* __restrict__ counter, int* __restrict__ list) {
    __shared__ __align__(16) char smem[36864];
    const int tid = threadIdx.x;
    const int l = tid & 63, w = tid >> 6;
    const int m31 = l & 31, h = l >> 5, h4 = h * 4;
    const int rowbase = blockIdx.x * 256 + w * 64;

    uint4 p0, p1, p2, p3;
    stage_load(0, tid, chi, clo, p0, p1, p2, p3);
    *(float4*)(smem + 32768 + tid * 16) =
        *(const float4*)((const char*)c2 + tid * 16);

    uint4 bh0[8], bl0[8], bh1[8], bl1[8];
    load_row(latent + (size_t)(rowbase + m31) * D, h, bh0, bl0);
    load_row(latent + (size_t)(rowbase + 32 + m31) * D, h, bh1, bl1);
    stage_write(0, tid, p0, p1, p2, p3, smem);
    __syncthreads();

    float m1_0 = 3.4e38f, m2_0 = 3.4e38f, m1_1 = 3.4e38f, m2_1 = 3.4e38f;
    int i1_0 = 0, i1_1 = 0;
    const float* c2l = (const float*)(smem + 32768);

#pragma unroll 1
    for (int t = 0; t < 32; ++t) {
        const int buf = t & 1;
        uint4 s0, s1, s2, s3;
        if (t + 1 < 32) stage_load(t + 1, tid, chi, clo, s0, s1, s2, s3);

        const int k0 = t * 32;
        f32x16 a0, a1;
#pragma unroll
        for (int q = 0; q < 4; ++q) {
            float4 cq = *(const float4*)(c2l + k0 + 8 * q + h4);
            a0[4 * q + 0] = cq.x;
            a0[4 * q + 1] = cq.y;
            a0[4 * q + 2] = cq.z;
            a0[4 * q + 3] = cq.w;
        }
        a1 = a0;

        const char* lhs = smem + buf * 16384;
#pragma unroll
        for (int c = 0; c < 8; ++c) {
            const int sw = (((2 * c + h) ^ (m31 & 15)) << 4) + m31 * 256;
            short8 ahi = *(const short8*)(lhs + sw);
            short8 alo = *(const short8*)(lhs + 8192 + sw);
            a0 = __builtin_amdgcn_mfma_f32_32x32x16_bf16(ahi, as_s8(bh0[c]), a0, 0, 0, 0);
            a1 = __builtin_amdgcn_mfma_f32_32x32x16_bf16(ahi, as_s8(bh1[c]), a1, 0, 0, 0);
            a0 = __builtin_amdgcn_mfma_f32_32x32x16_bf16(ahi, as_s8(bl0[c]), a0, 0, 0, 0);
            a1 = __builtin_amdgcn_mfma_f32_32x32x16_bf16(ahi, as_s8(bl1[c]), a1, 0, 0, 0);
            a0 = __builtin_amdgcn_mfma_f32_32x32x16_bf16(alo, as_s8(bh0[c]), a0, 0, 0, 0);
            a1 = __builtin_amdgcn_mfma_f32_32x32x16_bf16(alo, as_s8(bh1[c]), a1, 0, 0, 0);
        }

#pragma unroll
        for (int q = 0; q < 4; ++q) {
#pragma unroll
            for (int j = 0; j < 4; ++j) {
                const int r = 4 * q + j;
                const int kk = k0 + 8 * q + j + h4;
                float v0 = a0[r], v1 = a1[r];
                bool lt0 = v0 < m1_0, lt1 = v1 < m1_1;
                m2_0 = fminf(m2_0, fmaxf(v0, m1_0));
                m2_1 = fminf(m2_1, fmaxf(v1, m1_1));
                m1_0 = fminf(m1_0, v0);
                m1_1 = fminf(m1_1, v1);
                i1_0 = lt0 ? kk : i1_0;
                i1_1 = lt1 ? kk : i1_1;
            }
        }

        if (t + 1 < 32) stage_write(buf ^ 1, tid, s0, s1, s2, s3, smem);
        __syncthreads();
    }

    // merge the two k-halves (lane l <-> l+32); tie -> lower k
    {
        float om = __shfl_xor(m1_0, 32);
        int oi = __shfl_xor(i1_0, 32);
        float o2 = __shfl_xor(m2_0, 32);
        m2_0 = fminf(fminf(m2_0, o2), fmaxf(m1_0, om));
        bool take = (om < m1_0) || (om == m1_0 && oi < i1_0);
        m1_0 = fminf(m1_0, om);
        i1_0 = take ? oi : i1_0;
    }
    {
        float om = __shfl_xor(m1_1, 32);
        int oi = __shfl_xor(i1_1, 32);
        float o2 = __shfl_xor(m2_1, 32);
        m2_1 = fminf(fminf(m2_1, o2), fmaxf(m1_1, om));
        bool take = (om < m1_1) || (om == m1_1 && oi < i1_1);
        m1_1 = fminf(m1_1, om);
        i1_1 = take ? oi : i1_1;
    }

    const float mym1 = (l < 32) ? m1_0 : m1_1;
    const float mym2 = (l < 32) ? m2_0 : m2_1;
    const int myi = (l < 32) ? i1_0 : i1_1;
    out[rowbase + l] = myi;

    const bool flg = (mym2 - mym1) <= EPS2;
    unsigned long long bm = __ballot(flg);
    int cnt = __popcll(bm);
    int pos = 0;
    if (l == 0 && cnt) pos = atomicAdd(counter, cnt);
    pos = __shfl(pos, 0);
    if (flg)
        list[pos + __popcll(bm & ((1ull << l) - 1ull))] = rowbase + l;
}

// ---- pass B: exact fp32 recompute, 4 rows/wave-task, coalesced coordsT ----
__global__ __launch_bounds__(256) void centroid_exact_kernel(
    const float* __restrict__ latent, const float* __restrict__ coordsT,
    const float* __restrict__ c2, const int* __restrict__ cnt_list,
    int* __restrict__ out) {
    const int count = cnt_list[0];
    const int* list = cnt_list + 16;
    const int lane = threadIdx.x & 63;
    const int gw = (blockIdx.x * 256 + threadIdx.x) >> 6;
    const int nwaves = gridDim.x * 4;
    // lane owns k = c*64 + lane, c = 0..15 (coalesced coordsT reads)

    for (int task = gw; task * 4 < count; task += nwaves) {
        const int base = task * 4;
        const int nr = min(4, count - base);
        const float* xp[4];
        int rows[4];
#pragma unroll
        for (int j = 0; j < 4; ++j) {
            int idx = base + (j < nr ? j : nr - 1);
            rows[j] = __builtin_amdgcn_readfirstlane(list[idx]);
            xp[j] = latent + (size_t)rows[j] * D;
        }

        float acc[16][4];
#pragma unroll
        for (int c = 0; c < 16; ++c) {
            float cc = c2[c * 64 + lane];
#pragma unroll
            for (int j = 0; j < 4; ++j) acc[c][j] = cc;
        }

#pragma unroll 1
        for (int d4 = 0; d4 < D / 4; ++d4) {
            float4 xq[4];
#pragma unroll
            for (int j = 0; j < 4; ++j)
                xq[j] = *(const float4*)(xp[j] + 4 * d4);
            float ct[4][16];
#pragma unroll
            for (int dd = 0; dd < 4; ++dd)
#pragma unroll
                for (int c = 0; c < 16; ++c)
                    ct[dd][c] = coordsT[(size_t)(4 * d4 + dd) * K + c * 64 + lane];
            // per-(row,k) chain: scalar fmaf ascending d (== r1-proven order)
#pragma unroll
            for (int dd = 0; dd < 4; ++dd) {
#pragma unroll
                for (int c = 0; c < 16; ++c) {
#pragma unroll
                    for (int j = 0; j < 4; ++j) {
                        float xv = (dd == 0) ? xq[j].x
                                 : (dd == 1) ? xq[j].y
                                 : (dd == 2) ? xq[j].z : xq[j].w;
                        acc[c][j] = fmaf(-xv, ct[dd][c], acc[c][j]);
                    }
                }
            }
        }

#pragma unroll
        for (int j = 0; j < 4; ++j) {
            float m1 = acc[0][j];
            int i1 = lane; // k = 0*64 + lane
#pragma unroll
            for (int c = 1; c < 16; ++c) { // ascending c == ascending k
                const int kk = c * 64 + lane;
                if (acc[c][j] < m1) { m1 = acc[c][j]; i1 = kk; }
            }
#pragma unroll
            for (int off = 1; off < 64; off <<= 1) {
                float om = __shfl_xor(m1, off);
                int oi = __shfl_xor(i1, off);
                if (om < m1 || (om == m1 && oi < i1)) { m1 = om; i1 = oi; }
            }
            if (lane == 0 && j < nr) out[rows[j]] = i1;
        }
    }
}

extern "C" void kernel_launch(void* const* d_in, const int* in_sizes, int n_in,
                              void* d_out, int out_size, void* d_ws, size_t ws_size,
                              hipStream_t stream) {
    const float* latent = (const float*)d_in[0];
    const float* coords = (const float*)d_in[1];
    int* out = (int*)d_out;

    char* ws = (char*)d_ws;
    float* c2 = (float*)ws;                          // 4 KB
    uint* chi = (uint*)(ws + 4096);                  // 256 KB
    uint* clo = (uint*)(ws + 4096 + 262144);         // 256 KB
    float* coordsT = (float*)(ws + 4096 + 2 * 262144);       // 512 KB
    int* cnt_list = (int*)(ws + 4096 + 2 * 262144 + 524288); // 64 B + 512 KB list
    int* counter = cnt_list;
    int* list = cnt_list + 16;

    centroid_c2_kernel<<<(K + 255) / 256, 256, 0, stream>>>(coords, c2, counter);
    split_kernel<<<(K * D / 2) / 256, 256, 0, stream>>>(coords, chi, clo);
    {
        dim3 g(K / 64, D / 64);
        transpose_kernel<<<g, 256, 0, stream>>>(coords, coordsT);
    }
    centroid_mfma_kernel<<<N / 256, 256, 0, stream>>>(latent, chi, clo, c2, out,
                                                      counter, list);
    centroid_exact_kernel<<<2048, 256, 0, stream>>>(latent, coordsT, c2, cnt_list, out);
}